// Round 1
// baseline (277.038 us; speedup 1.0000x reference)
//
#include <hip/hip_runtime.h>
#include <math.h>

#define IMG 512
#define NPIX (64 * 512 * 512)

// constants + accumulators (rewritten deterministically every launch)
// [0..27]  E[4][7]   exp vectors for sigma {0.5,1,2,4}
// [28..48] V[3][7]   (x^2/2s^2)*E for LoG sigmas {1,2,4}
// [49..51] invS4[3]  1/gsum^2 for gaussian sigmas {0.5,1,2}
// [52..54] invN2[3]  1/norm^2 for LoG sigmas {1,2,4}
// [60] loss accumulator, [61] target-sum accumulator
__device__ float g_c[64];

__device__ __forceinline__ float rdfl(float x) {
    return __uint_as_float(__builtin_amdgcn_readfirstlane(__float_as_uint(x)));
}

__global__ void precompute_kernel() {
    if (threadIdx.x != 0 || blockIdx.x != 0) return;
    // torch.linspace(-4, 3, 7): computed in f64, cast to f32, endpoint exact
    const double step = 7.0 / 6.0;
    float x[7];
    for (int j = 0; j < 7; j++) x[j] = (float)(-4.0 + j * step);
    x[6] = 3.0f;
    const float sigs[4] = {0.5f, 1.0f, 2.0f, 4.0f};
    float E[4][7], Q[4][7];
    for (int s = 0; s < 4; s++) {
        float inv = 1.0f / (2.0f * sigs[s] * sigs[s]);
        for (int j = 0; j < 7; j++) {
            float q = x[j] * x[j] * inv;
            Q[s][j] = q;
            E[s][j] = expf(-q);
        }
    }
    for (int s = 0; s < 4; s++)
        for (int j = 0; j < 7; j++) g_c[s * 7 + j] = E[s][j];
    for (int s = 1; s < 4; s++)
        for (int j = 0; j < 7; j++) g_c[28 + (s - 1) * 7 + j] = Q[s][j] * E[s][j];
    // gaussian: kernel = outer(E,E)/gsum ; fold 1/gsum^2 into squared output
    for (int s = 0; s < 3; s++) {
        float gs = 0.f;
        for (int i = 0; i < 7; i++)
            for (int j = 0; j < 7; j++) gs += E[s][i] * E[s][j];
        g_c[49 + s] = 1.0f / (gs * gs);
    }
    // LoG: kernel = (E⊗E − V⊗E − E⊗V)/n, n = L1 norm of raw kernel
    for (int s = 1; s < 4; s++) {
        float n = 0.f;
        for (int i = 0; i < 7; i++)
            for (int j = 0; j < 7; j++) {
                float v = E[s][i] * E[s][j] * (1.0f - Q[s][i] - Q[s][j]);
                n += fabsf(v);
            }
        g_c[52 + (s - 1)] = 1.0f / (n * n);
    }
    g_c[60] = 0.f;
    g_c[61] = 0.f;
}

__global__ __launch_bounds__(256) void sum_target_kernel(const float4* __restrict__ t4) {
    int tid = blockIdx.x * 256 + threadIdx.x;
    float s = 0.f;
    for (int i = tid; i < NPIX / 4; i += 2048 * 256) {
        float4 v = t4[i];
        s += (v.x + v.y) + (v.z + v.w);
    }
    for (int off = 32; off > 0; off >>= 1) s += __shfl_down(s, off);
    __shared__ float ps[4];
    int lane = threadIdx.x & 63, wid = threadIdx.x >> 6;
    if (lane == 0) ps[wid] = s;
    __syncthreads();
    if (threadIdx.x == 0) atomicAdd(&g_c[61], (ps[0] + ps[1]) + (ps[2] + ps[3]));
}

__global__ __launch_bounds__(256) void main_kernel(const float* __restrict__ R,
                                                   const float* __restrict__ T) {
    __shared__ float sd[38][40];   // d = r - t, halo 3, zero-padded
    __shared__ float sr[34][36];   // r, halo 1, -inf padded (maxpool)
    __shared__ float st[34][36];   // t, halo 1, -inf padded
    __shared__ float red[4];

    const int tx = threadIdx.x, ty = threadIdx.y;
    const int tid = ty * 16 + tx;
    const int gx0 = blockIdx.x * 32, gy0 = blockIdx.y * 32;
    const int base = blockIdx.z * (IMG * IMG);

    for (int idx = tid; idx < 38 * 38; idx += 256) {
        int i = idx / 38, j = idx - i * 38;
        int gy = gy0 + i - 3, gx = gx0 + j - 3;
        bool in = ((unsigned)gy < IMG) && ((unsigned)gx < IMG);
        float rv = 0.f, tv = 0.f;
        if (in) {
            int o = base + gy * IMG + gx;
            rv = R[o];
            tv = T[o];
        }
        sd[i][j] = rv - tv;
        if (i >= 2 && i < 36 && j >= 2 && j < 36) {
            sr[i - 2][j - 2] = in ? rv : -INFINITY;
            st[i - 2][j - 2] = in ? tv : -INFINITY;
        }
    }
    __syncthreads();

    // uniform coefficients -> SGPRs
    float E[4][7], V[3][7];
#pragma unroll
    for (int s = 0; s < 4; s++)
#pragma unroll
        for (int j = 0; j < 7; j++) E[s][j] = rdfl(g_c[s * 7 + j]);
#pragma unroll
    for (int s = 0; s < 3; s++)
#pragma unroll
        for (int j = 0; j < 7; j++) V[s][j] = rdfl(g_c[28 + s * 7 + j]);
    float invS4[3], invN2[3];
#pragma unroll
    for (int s = 0; s < 3; s++) {
        invS4[s] = rdfl(g_c[49 + s]);
        invN2[s] = rdfl(g_c[52 + s]);
    }
    const float mean = rdfl(g_c[61]) * (1.0f / (float)NPIX);

    const int x0 = tx * 2, y0 = ty * 2;

    float accG[3][2][2] = {};
    float accL[3][2][2] = {};

#pragma unroll
    for (int i = 0; i < 8; i++) {
        float row[8];
#pragma unroll
        for (int j = 0; j < 8; j++) row[j] = sd[y0 + i][x0 + j];
        float HE[4][2], HV[3][2], Tm[3][2];
#pragma unroll
        for (int b = 0; b < 2; b++) {
#pragma unroll
            for (int s = 0; s < 4; s++) {
                float h = 0.f;
#pragma unroll
                for (int j = 0; j < 7; j++) h += E[s][j] * row[j + b];
                HE[s][b] = h;
            }
#pragma unroll
            for (int s = 0; s < 3; s++) {
                float h = 0.f;
#pragma unroll
                for (int j = 0; j < 7; j++) h += V[s][j] * row[j + b];
                HV[s][b] = h;
                Tm[s][b] = HE[s + 1][b] - h;
            }
        }
#pragma unroll
        for (int a = 0; a < 2; a++) {
            const int ki = i - a;
            if (ki >= 0 && ki <= 6) {
#pragma unroll
                for (int b = 0; b < 2; b++) {
#pragma unroll
                    for (int s = 0; s < 3; s++) accG[s][a][b] += E[s][ki] * HE[s][b];
#pragma unroll
                    for (int s = 0; s < 3; s++)
                        accL[s][a][b] += E[s + 1][ki] * Tm[s][b] - V[s][ki] * HE[s + 1][b];
                }
            }
        }
    }

    float p[4][4], qr[4][4], qt[4][4];
#pragma unroll
    for (int u = 0; u < 4; u++)
#pragma unroll
        for (int v = 0; v < 4; v++) {
            p[u][v] = sd[y0 + 2 + u][x0 + 2 + v];
            qr[u][v] = sr[y0 + u][x0 + v];
            qt[u][v] = st[y0 + u][x0 + v];
        }

    float total = 0.f;
#pragma unroll
    for (int a = 0; a < 2; a++)
#pragma unroll
        for (int b = 0; b < 2; b++) {
            float sx = (p[a][b + 2] - p[a][b]) + 2.f * (p[a + 1][b + 2] - p[a + 1][b]) +
                       (p[a + 2][b + 2] - p[a + 2][b]);
            float sy = (p[a + 2][b] - p[a][b]) + 2.f * (p[a + 2][b + 1] - p[a][b + 1]) +
                       (p[a + 2][b + 2] - p[a][b + 2]);
            float pt = 4.f * p[a + 1][b + 1] - p[a][b + 1] - p[a + 1][b] - p[a + 1][b + 2] -
                       p[a + 2][b + 1];
            float d = p[a + 1][b + 1];
            float tv = qt[a + 1][b + 1];
            float wsq = (tv > mean) ? 9.f : 1.f;

            float mr = fmaxf(fmaxf(fmaxf(qr[a][b], qr[a][b + 1]), fmaxf(qr[a][b + 2], qr[a + 1][b])),
                             fmaxf(fmaxf(qr[a + 1][b + 1], qr[a + 1][b + 2]),
                                   fmaxf(fmaxf(qr[a + 2][b], qr[a + 2][b + 1]), qr[a + 2][b + 2])));
            float mt = fmaxf(fmaxf(fmaxf(qt[a][b], qt[a][b + 1]), fmaxf(qt[a][b + 2], qt[a + 1][b])),
                             fmaxf(fmaxf(qt[a + 1][b + 1], qt[a + 1][b + 2]),
                                   fmaxf(fmaxf(qt[a + 2][b], qt[a + 2][b + 1]), qt[a + 2][b + 2])));

            float sStruct = invS4[0] * accG[0][a][b] * accG[0][a][b] +
                            invS4[1] * accG[1][a][b] * accG[1][a][b] +
                            invS4[2] * accG[2][a][b] * accG[2][a][b];
            float sScale = invN2[0] * accL[0][a][b] * accL[0][a][b] +
                           invN2[1] * accL[1][a][b] * accL[1][a][b] +
                           invN2[2] * accL[2][a][b] * accL[2][a][b];

            total += wsq * d * d + 2.f * (sx * sx + sy * sy) + 1.5f * pt * pt + sStruct +
                     sScale + 2.f * fabsf(mr - mt);
        }

    for (int off = 32; off > 0; off >>= 1) total += __shfl_down(total, off);
    int lane = tid & 63, wid = tid >> 6;
    if (lane == 0) red[wid] = total;
    __syncthreads();
    if (tid == 0) atomicAdd(&g_c[60], (red[0] + red[1]) + (red[2] + red[3]));
}

__global__ void finalize_kernel(float* __restrict__ out) {
    if (threadIdx.x == 0 && blockIdx.x == 0) out[0] = g_c[60] * (1.0f / (float)NPIX);
}

extern "C" void kernel_launch(void* const* d_in, const int* in_sizes, int n_in,
                              void* d_out, int out_size, void* d_ws, size_t ws_size,
                              hipStream_t stream) {
    const float* recon = (const float*)d_in[0];
    const float* target = (const float*)d_in[1];

    hipLaunchKernelGGL(precompute_kernel, dim3(1), dim3(64), 0, stream);
    hipLaunchKernelGGL(sum_target_kernel, dim3(2048), dim3(256), 0, stream,
                       (const float4*)target);
    dim3 grid(16, 16, 64), block(16, 16);
    hipLaunchKernelGGL(main_kernel, grid, block, 0, stream, recon, target);
    hipLaunchKernelGGL(finalize_kernel, dim3(1), dim3(1), 0, stream, (float*)d_out);
}